// Round 1
// baseline (2559.358 us; speedup 1.0000x reference)
//
#include <hip/hip_runtime.h>
#include <cstdint>
#include <cstddef>

#define Bq 256
#define Tq 1024
#define Sq 7
#define Hq 64
#define Lq 4
#define OUTq 3

// One wave (64 lanes) per batch element. Lane = hidden unit.
// Weights register-resident: wl[3][64] = w_h[l][lane][j] (contiguous row load).
// Spike mask via __ballot (wave-uniform SGPR pair); per-bit 1.0/0.0 select is
// scalar-pipe work feeding v_fma_f32 with SGPR src0 -> 1 VALU op per bit.
__global__ __launch_bounds__(64, 1) void snn_seq_kernel(
    const float* __restrict__ x,       // (B,T,S)
    const float* __restrict__ hs_in,   // (B,T,L,H)
    const float* __restrict__ w1,      // (H,S)
    const float* __restrict__ b1,      // (H)
    const float* __restrict__ w_h,     // (L-1,H,H)
    const float* __restrict__ b_h,     // (L-1,H)
    float* __restrict__ out_mem)       // (B,T,L,H)
{
    const int b = blockIdx.x;
    const int lane = threadIdx.x; // 0..63

    // --- load per-lane weights into registers ---
    float w1r[Sq];
#pragma unroll
    for (int s = 0; s < Sq; ++s) w1r[s] = w1[lane * Sq + s];
    const float b1r = b1[lane];

    float wl[3][Hq];
#pragma unroll
    for (int l = 0; l < 3; ++l) {
        const float4* src = (const float4*)(w_h + ((size_t)(l * Hq + lane)) * Hq);
#pragma unroll
        for (int q = 0; q < Hq / 4; ++q) {
            float4 v = src[q];
            wl[l][4 * q + 0] = v.x;
            wl[l][4 * q + 1] = v.y;
            wl[l][4 * q + 2] = v.z;
            wl[l][4 * q + 3] = v.w;
        }
    }
    float bhr[3];
#pragma unroll
    for (int l = 0; l < 3; ++l) bhr[l] = b_h[l * Hq + lane];

    // --- init membrane state from hidden_states[:,0] ---
    float m[Lq];
#pragma unroll
    for (int l = 0; l < Lq; ++l) m[l] = hs_in[(((size_t)b * Tq + 0) * Lq + l) * Hq + lane];

    const float* xrow = x + (size_t)b * Tq * Sq;  // wave-uniform addresses
    float xv[Sq];
#pragma unroll
    for (int s = 0; s < Sq; ++s) xv[s] = xrow[s];

    float* omem = out_mem + (size_t)b * Tq * Lq * Hq + lane;

    for (int t = 0; t < Tq; ++t) {
        // prefetch next timestep's x row (uniform -> scalar loads, hides latency)
        const float* xn_p = xrow + (t < Tq - 1 ? (t + 1) * Sq : t * Sq);
        float xn[Sq];
#pragma unroll
        for (int s = 0; s < Sq; ++s) xn[s] = xn_p[s];

        // input projection: all_cur[b,t,lane]
        float cur = b1r;
#pragma unroll
        for (int s = 0; s < Sq; ++s) cur = fmaf(xv[s], w1r[s], cur);

        float* om_t = omem + (size_t)t * Lq * Hq;
#pragma unroll
        for (int l = 0; l < Lq; ++l) {
            float mp = m[l];
            float rst = (mp > 1.0f) ? 1.0f : 0.0f;
            // match numpy op order: 0.8*m + cur - reset  (no fma contraction)
            float mn = __fadd_rn(__fmul_rn(0.8f, mp), cur);
            mn = __fsub_rn(mn, rst);
            m[l] = mn;
            om_t[l * Hq] = mn;  // coalesced 256B store, fire-and-forget

            if (l < 3) {
                unsigned long long mask = __ballot(mn > 1.0f);  // wave-uniform
                float a0 = bhr[l], a1 = 0.0f, a2 = 0.0f, a3 = 0.0f;
#pragma unroll
                for (int j = 0; j < Hq; j += 4) {
                    float f0 = ((mask >> (j + 0)) & 1ull) ? 1.0f : 0.0f;
                    float f1 = ((mask >> (j + 1)) & 1ull) ? 1.0f : 0.0f;
                    float f2 = ((mask >> (j + 2)) & 1ull) ? 1.0f : 0.0f;
                    float f3 = ((mask >> (j + 3)) & 1ull) ? 1.0f : 0.0f;
                    a0 = fmaf(f0, wl[l][j + 0], a0);
                    a1 = fmaf(f1, wl[l][j + 1], a1);
                    a2 = fmaf(f2, wl[l][j + 2], a2);
                    a3 = fmaf(f3, wl[l][j + 3], a3);
                }
                cur = __fadd_rn(__fadd_rn(a0, a1), __fadd_rn(a2, a3));
            }
        }
#pragma unroll
        for (int s = 0; s < Sq; ++s) xv[s] = xn[s];
    }
}

// Readout deferred out of the sequential path: recompute layer-3 spikes from
// the stored membrane states (already in d_out) fully in parallel.
// One wave per (b,t): coalesced 256B read, 3 shuffle-reductions.
__global__ __launch_bounds__(256) void snn_out_kernel(
    const float* __restrict__ mem,    // (B,T,L,H)
    const float* __restrict__ w_out,  // (OUT,H)
    const float* __restrict__ b_out,  // (OUT)
    float* __restrict__ out0)         // (B,T,OUT)
{
    const int lane = threadIdx.x & 63;
    const int wv = threadIdx.x >> 6;
    const long long idx = (long long)blockIdx.x * 4 + wv;  // = b*T + t
    if (idx >= (long long)Bq * Tq) return;
    float mval = mem[((size_t)idx * Lq + 3) * Hq + lane];
    float s = (mval > 1.0f) ? 1.0f : 0.0f;
#pragma unroll
    for (int o = 0; o < OUTq; ++o) {
        float v = s * w_out[o * Hq + lane];
#pragma unroll
        for (int off = 32; off > 0; off >>= 1) v += __shfl_xor(v, off, 64);
        if (lane == 0) out0[idx * OUTq + o] = v + b_out[o];
    }
}

__global__ __launch_bounds__(256) void copy_x_kernel(
    const float4* __restrict__ src, float4* __restrict__ dst, int n4)
{
    int i = blockIdx.x * 256 + threadIdx.x;
    if (i < n4) dst[i] = src[i];
}

extern "C" void kernel_launch(void* const* d_in, const int* in_sizes, int n_in,
                              void* d_out, int out_size, void* d_ws, size_t ws_size,
                              hipStream_t stream) {
    const float* x     = (const float*)d_in[0];
    const float* hs_in = (const float*)d_in[1];
    // d_in[2] = prev_obs (unused by reference)
    const float* w1    = (const float*)d_in[3];
    const float* b1    = (const float*)d_in[4];
    const float* w_h   = (const float*)d_in[5];
    const float* b_h   = (const float*)d_in[6];
    const float* w_out = (const float*)d_in[7];
    const float* b_out = (const float*)d_in[8];

    float* out0 = (float*)d_out;                                   // (B,T,OUT)
    float* out1 = out0 + (size_t)Bq * Tq * OUTq;                   // (B,T,L,H)
    float* out2 = out1 + (size_t)Bq * Tq * Lq * Hq;                // (B,T,S) = x

    // 1) sequential SNN scan: writes new_hidden_states
    snn_seq_kernel<<<Bq, 64, 0, stream>>>(x, hs_in, w1, b1, w_h, b_h, out1);

    // 2) readout from stored layer-3 membranes
    const long long nbt = (long long)Bq * Tq;
    snn_out_kernel<<<(int)(nbt / 4), 256, 0, stream>>>(out1, w_out, b_out, out0);

    // 3) passthrough copy of x
    const int n4 = Bq * Tq * Sq / 4;
    copy_x_kernel<<<(n4 + 255) / 256, 256, 0, stream>>>((const float4*)x, (float4*)out2, n4);
}

// Round 2
// 2518.805 us; speedup vs baseline: 1.0161x; 1.0161x over previous
//
#include <hip/hip_runtime.h>
#include <cstdint>
#include <cstddef>

#define Bq 256
#define Tq 1024
#define Sq 7
#define Hq 64
#define Lq 4
#define OUTq 3

// One wave (64 lanes) per batch element. Lane = hidden unit.
// Recurrent weights live in LDS (48 KB), packed so the inner loop is
// ds_read_b128 per 4 columns: wq[l][q][lane] = w_h[l][lane][4q..4q+3].
// Spike factors come from the wave-uniform __ballot mask via scalar-pipe
// bit tests feeding v_fma_f32 with an SGPR operand.
// Accumulation order identical to the passing R1 kernel (4 accumulators,
// j stride 4) to keep numerics bit-stable through the spike thresholds.
__global__ __launch_bounds__(64, 1) void snn_seq_kernel(
    const float* __restrict__ x,       // (B,T,S)
    const float* __restrict__ hs_in,   // (B,T,L,H)
    const float* __restrict__ w1,      // (H,S)
    const float* __restrict__ b1,      // (H)
    const float* __restrict__ w_h,     // (L-1,H,H)
    const float* __restrict__ b_h,     // (L-1,H)
    float* __restrict__ out_mem)       // (B,T,L,H)
{
    __shared__ float4 wq[3][16][Hq];   // 3*16*64*16B = 48 KB

    const int b = blockIdx.x;
    const int lane = threadIdx.x; // 0..63

    // --- stage recurrent weights into LDS (once) ---
#pragma unroll
    for (int l = 0; l < 3; ++l) {
        const float4* src = (const float4*)(w_h + ((size_t)(l * Hq + lane)) * Hq);
#pragma unroll
        for (int q = 0; q < 16; ++q) wq[l][q][lane] = src[q];
    }

    // --- per-lane small weights in registers ---
    float w1r[Sq];
#pragma unroll
    for (int s = 0; s < Sq; ++s) w1r[s] = w1[lane * Sq + s];
    const float b1r = b1[lane];
    float bhr[3];
#pragma unroll
    for (int l = 0; l < 3; ++l) bhr[l] = b_h[l * Hq + lane];

    // --- init membrane state from hidden_states[:,0] ---
    float m[Lq];
#pragma unroll
    for (int l = 0; l < Lq; ++l) m[l] = hs_in[(((size_t)b * Tq + 0) * Lq + l) * Hq + lane];

    const float* xrow = x + (size_t)b * Tq * Sq;  // wave-uniform addresses
    float xv[Sq];
#pragma unroll
    for (int s = 0; s < Sq; ++s) xv[s] = xrow[s];

    float* omem = out_mem + (size_t)b * Tq * Lq * Hq + lane;

    __syncthreads();

    for (int t = 0; t < Tq; ++t) {
        // prefetch next timestep's x row (uniform -> hides global latency)
        const float* xn_p = xrow + (t < Tq - 1 ? (t + 1) * Sq : t * Sq);
        float xn[Sq];
#pragma unroll
        for (int s = 0; s < Sq; ++s) xn[s] = xn_p[s];

        // input projection: all_cur[b,t,lane]
        float cur = b1r;
#pragma unroll
        for (int s = 0; s < Sq; ++s) cur = fmaf(xv[s], w1r[s], cur);

        float* om_t = omem + (size_t)t * Lq * Hq;
#pragma unroll
        for (int l = 0; l < Lq; ++l) {
            float mp = m[l];
            float rst = (mp > 1.0f) ? 1.0f : 0.0f;
            // match numpy op order: 0.8*m + cur - reset  (no fma contraction)
            float mn = __fadd_rn(__fmul_rn(0.8f, mp), cur);
            mn = __fsub_rn(mn, rst);
            m[l] = mn;
            om_t[l * Hq] = mn;  // coalesced 256B store, fire-and-forget

            if (l < 3) {
                unsigned long long mask = __ballot(mn > 1.0f);  // wave-uniform
                float a0 = bhr[l], a1 = 0.0f, a2 = 0.0f, a3 = 0.0f;
#pragma unroll
                for (int q = 0; q < 16; ++q) {
                    float4 w = wq[l][q][lane];          // ds_read_b128
                    float f0 = ((mask >> (4 * q + 0)) & 1ull) ? 1.0f : 0.0f;
                    float f1 = ((mask >> (4 * q + 1)) & 1ull) ? 1.0f : 0.0f;
                    float f2 = ((mask >> (4 * q + 2)) & 1ull) ? 1.0f : 0.0f;
                    float f3 = ((mask >> (4 * q + 3)) & 1ull) ? 1.0f : 0.0f;
                    a0 = fmaf(f0, w.x, a0);
                    a1 = fmaf(f1, w.y, a1);
                    a2 = fmaf(f2, w.z, a2);
                    a3 = fmaf(f3, w.w, a3);
                }
                cur = __fadd_rn(__fadd_rn(a0, a1), __fadd_rn(a2, a3));
            }
        }
#pragma unroll
        for (int s = 0; s < Sq; ++s) xv[s] = xn[s];
    }
}

// Readout deferred out of the sequential path: recompute layer-3 spikes from
// the stored membrane states. 16 lanes per (b,t) row: float4 load (coalesced),
// 4 fma + 4-step shuffle reduce per output.
__global__ __launch_bounds__(256) void snn_out_kernel(
    const float* __restrict__ mem,    // (B,T,L,H)
    const float* __restrict__ w_out,  // (OUT,H)
    const float* __restrict__ b_out,  // (OUT)
    float* __restrict__ out0)         // (B,T,OUT)
{
    const long long idx = (long long)blockIdx.x * 16 + (threadIdx.x >> 4); // b*T + t
    const int sub = threadIdx.x & 15;
    if (idx >= (long long)Bq * Tq) return;

    // layer-3 row: floats [idx*256+192 .. +255] -> float4 index idx*64+48+sub
    float4 mv = ((const float4*)mem)[(size_t)idx * 64 + 48 + sub];
    float4 s;
    s.x = (mv.x > 1.0f) ? 1.0f : 0.0f;
    s.y = (mv.y > 1.0f) ? 1.0f : 0.0f;
    s.z = (mv.z > 1.0f) ? 1.0f : 0.0f;
    s.w = (mv.w > 1.0f) ? 1.0f : 0.0f;

#pragma unroll
    for (int o = 0; o < OUTq; ++o) {
        float4 wv = ((const float4*)w_out)[o * 16 + sub];
        float v = s.x * wv.x + s.y * wv.y + s.z * wv.z + s.w * wv.w;
#pragma unroll
        for (int off = 8; off > 0; off >>= 1) v += __shfl_xor(v, off, 16);
        if (sub == 0) out0[idx * OUTq + o] = v + b_out[o];
    }
}

__global__ __launch_bounds__(256) void copy_x_kernel(
    const float4* __restrict__ src, float4* __restrict__ dst, int n4)
{
    int i = blockIdx.x * 256 + threadIdx.x;
    if (i < n4) dst[i] = src[i];
}

extern "C" void kernel_launch(void* const* d_in, const int* in_sizes, int n_in,
                              void* d_out, int out_size, void* d_ws, size_t ws_size,
                              hipStream_t stream) {
    const float* x     = (const float*)d_in[0];
    const float* hs_in = (const float*)d_in[1];
    // d_in[2] = prev_obs (unused by reference)
    const float* w1    = (const float*)d_in[3];
    const float* b1    = (const float*)d_in[4];
    const float* w_h   = (const float*)d_in[5];
    const float* b_h   = (const float*)d_in[6];
    const float* w_out = (const float*)d_in[7];
    const float* b_out = (const float*)d_in[8];

    float* out0 = (float*)d_out;                                   // (B,T,OUT)
    float* out1 = out0 + (size_t)Bq * Tq * OUTq;                   // (B,T,L,H)
    float* out2 = out1 + (size_t)Bq * Tq * Lq * Hq;                // (B,T,S) = x

    // 1) sequential SNN scan: writes new_hidden_states
    snn_seq_kernel<<<Bq, 64, 0, stream>>>(x, hs_in, w1, b1, w_h, b_h, out1);

    // 2) readout from stored layer-3 membranes (16 lanes per row)
    const long long nbt = (long long)Bq * Tq;
    snn_out_kernel<<<(int)(nbt / 16), 256, 0, stream>>>(out1, w_out, b_out, out0);

    // 3) passthrough copy of x
    const int n4 = Bq * Tq * Sq / 4;
    copy_x_kernel<<<(n4 + 255) / 256, 256, 0, stream>>>((const float4*)x, (float4*)out2, n4);
}

// Round 3
// 1017.251 us; speedup vs baseline: 2.5160x; 2.4761x over previous
//
#include <hip/hip_runtime.h>
#include <cstdint>
#include <cstddef>

#define Bq 256
#define Tq 1024
#define Sq 7
#define Hq 64
#define Lq 4
#define OUTq 3

typedef float vf16 __attribute__((ext_vector_type(16)));

// Systolic SNN scan: one block per batch element, 4 waves = 4 layers.
// Wave l at beat k processes timestep t = k - l. Layer weights live in
// each wave's registers (64 VGPRs as 4x vf16 -> no scratch, no per-step
// weight loads). Cross-wave traffic is only the 8-byte spike ballot mask,
// double-buffered in LDS. Beat sync is a raw s_barrier preceded by
// lgkmcnt(0) ONLY (not vmcnt), so the per-beat global m-store never
// stalls the pipeline.
// Numerics: identical op order to the R1/R2 passing kernels
// (4-accumulator j-mod-4 fma chains, (a0+a1)+(a2+a3) combine, explicit
// __f*_rn LIF update).
__global__ __launch_bounds__(256, 1) void snn_seq_kernel(
    const float* __restrict__ x,       // (B,T,S)
    const float* __restrict__ hs_in,   // (B,T,L,H)
    const float* __restrict__ w1,      // (H,S)
    const float* __restrict__ b1,      // (H)
    const float* __restrict__ w_h,     // (L-1,H,H)
    const float* __restrict__ b_h,     // (L-1,H)
    float* __restrict__ out_mem)       // (B,T,L,H)
{
    __shared__ unsigned long long lmask[2][Lq];  // [slot][producer layer]

    const int b = blockIdx.x;
    const int lane = threadIdx.x & 63;
    const int wv = threadIdx.x >> 6;   // 0..3 = layer index

    // membrane state for this wave's layer, init from hidden_states[:,0]
    float m = hs_in[(((size_t)b * Tq) * Lq + wv) * Hq + lane];
    float* omem = out_mem + ((size_t)b * Tq * Lq + wv) * Hq + lane;

    // wave-0 (input projection) state
    float w1r[Sq];
    float b1r = 0.0f;
    const float* xrow = x + (size_t)b * Tq * Sq;
    float xv[Sq];
    // waves 1..3 (recurrent) state: 64 weight floats in registers
    vf16 W0, W1, W2, W3;
    float bhr = 0.0f;

    if (wv == 0) {
#pragma unroll
        for (int s = 0; s < Sq; ++s) w1r[s] = w1[lane * Sq + s];
        b1r = b1[lane];
#pragma unroll
        for (int s = 0; s < Sq; ++s) xv[s] = xrow[s];
    } else {
        const vf16* wr = (const vf16*)(w_h + ((size_t)((wv - 1) * Hq + lane)) * Hq);
        W0 = wr[0]; W1 = wr[1]; W2 = wr[2]; W3 = wr[3];
        bhr = b_h[(wv - 1) * Hq + lane];
    }

#define DOBLK(Wv, word, base)                                        \
    {                                                                \
        _Pragma("unroll") for (int q = 0; q < 4; ++q)                \
        {                                                            \
            float f0 = ((word >> (base + 4 * q + 0)) & 1u) ? 1.0f : 0.0f; \
            float f1 = ((word >> (base + 4 * q + 1)) & 1u) ? 1.0f : 0.0f; \
            float f2 = ((word >> (base + 4 * q + 2)) & 1u) ? 1.0f : 0.0f; \
            float f3 = ((word >> (base + 4 * q + 3)) & 1u) ? 1.0f : 0.0f; \
            a0 = fmaf(f0, Wv[4 * q + 0], a0);                        \
            a1 = fmaf(f1, Wv[4 * q + 1], a1);                        \
            a2 = fmaf(f2, Wv[4 * q + 2], a2);                        \
            a3 = fmaf(f3, Wv[4 * q + 3], a3);                        \
        }                                                            \
    }

    for (int k = 0; k < Tq + Lq - 1; ++k) {
        if (wv == 0) {
            if (k < Tq) {
                // prefetch next x row (latency spans the rest of this beat)
                const float* xp = xrow + (size_t)(k < Tq - 1 ? k + 1 : k) * Sq;
                float xn[Sq];
#pragma unroll
                for (int s = 0; s < Sq; ++s) xn[s] = xp[s];

                float cur = b1r;
#pragma unroll
                for (int s = 0; s < Sq; ++s) cur = fmaf(xv[s], w1r[s], cur);

                float rst = (m > 1.0f) ? 1.0f : 0.0f;
                float mn = __fadd_rn(__fmul_rn(0.8f, m), cur);
                mn = __fsub_rn(mn, rst);
                m = mn;
                omem[(size_t)k * (Lq * Hq)] = mn;  // fire-and-forget

                unsigned long long msk = __ballot(mn > 1.0f);
                if (lane == 0) lmask[k & 1][0] = msk;
#pragma unroll
                for (int s = 0; s < Sq; ++s) xv[s] = xn[s];
            }
        } else {
            const int t = k - wv;
            if (t >= 0 && t < Tq) {
                // spike mask from previous layer, produced last beat
                uint2 mr = *((const uint2*)&lmask[(k - 1) & 1][wv - 1]);
                unsigned lo = (unsigned)__builtin_amdgcn_readfirstlane((int)mr.x);
                unsigned hi = (unsigned)__builtin_amdgcn_readfirstlane((int)mr.y);

                float a0 = bhr, a1 = 0.0f, a2 = 0.0f, a3 = 0.0f;
                DOBLK(W0, lo, 0)
                DOBLK(W1, lo, 16)
                DOBLK(W2, hi, 0)
                DOBLK(W3, hi, 16)
                float cur = __fadd_rn(__fadd_rn(a0, a1), __fadd_rn(a2, a3));

                float rst = (m > 1.0f) ? 1.0f : 0.0f;
                float mn = __fadd_rn(__fmul_rn(0.8f, m), cur);
                mn = __fsub_rn(mn, rst);
                m = mn;
                omem[(size_t)t * (Lq * Hq)] = mn;

                if (wv < Lq - 1) {
                    unsigned long long msk = __ballot(mn > 1.0f);
                    if (lane == 0) lmask[k & 1][wv] = msk;
                }
            }
        }
        // beat barrier: drain LDS (mask handoff) but NOT vmem stores
        asm volatile("s_waitcnt lgkmcnt(0)\n\ts_barrier" ::: "memory");
    }
#undef DOBLK
}

// Readout deferred out of the sequential path: recompute layer-3 spikes from
// the stored membrane states. 16 lanes per (b,t) row.
__global__ __launch_bounds__(256) void snn_out_kernel(
    const float* __restrict__ mem,    // (B,T,L,H)
    const float* __restrict__ w_out,  // (OUT,H)
    const float* __restrict__ b_out,  // (OUT)
    float* __restrict__ out0)         // (B,T,OUT)
{
    const long long idx = (long long)blockIdx.x * 16 + (threadIdx.x >> 4); // b*T + t
    const int sub = threadIdx.x & 15;
    if (idx >= (long long)Bq * Tq) return;

    float4 mv = ((const float4*)mem)[(size_t)idx * 64 + 48 + sub];
    float4 s;
    s.x = (mv.x > 1.0f) ? 1.0f : 0.0f;
    s.y = (mv.y > 1.0f) ? 1.0f : 0.0f;
    s.z = (mv.z > 1.0f) ? 1.0f : 0.0f;
    s.w = (mv.w > 1.0f) ? 1.0f : 0.0f;

#pragma unroll
    for (int o = 0; o < OUTq; ++o) {
        float4 wv = ((const float4*)w_out)[o * 16 + sub];
        float v = s.x * wv.x + s.y * wv.y + s.z * wv.z + s.w * wv.w;
#pragma unroll
        for (int off = 8; off > 0; off >>= 1) v += __shfl_xor(v, off, 16);
        if (sub == 0) out0[idx * OUTq + o] = v + b_out[o];
    }
}

__global__ __launch_bounds__(256) void copy_x_kernel(
    const float4* __restrict__ src, float4* __restrict__ dst, int n4)
{
    int i = blockIdx.x * 256 + threadIdx.x;
    if (i < n4) dst[i] = src[i];
}

extern "C" void kernel_launch(void* const* d_in, const int* in_sizes, int n_in,
                              void* d_out, int out_size, void* d_ws, size_t ws_size,
                              hipStream_t stream) {
    const float* x     = (const float*)d_in[0];
    const float* hs_in = (const float*)d_in[1];
    // d_in[2] = prev_obs (unused by reference)
    const float* w1    = (const float*)d_in[3];
    const float* b1    = (const float*)d_in[4];
    const float* w_h   = (const float*)d_in[5];
    const float* b_h   = (const float*)d_in[6];
    const float* w_out = (const float*)d_in[7];
    const float* b_out = (const float*)d_in[8];

    float* out0 = (float*)d_out;                                   // (B,T,OUT)
    float* out1 = out0 + (size_t)Bq * Tq * OUTq;                   // (B,T,L,H)
    float* out2 = out1 + (size_t)Bq * Tq * Lq * Hq;                // (B,T,S) = x

    // 1) systolic sequential SNN scan: writes new_hidden_states
    snn_seq_kernel<<<Bq, 256, 0, stream>>>(x, hs_in, w1, b1, w_h, b_h, out1);

    // 2) readout from stored layer-3 membranes
    const long long nbt = (long long)Bq * Tq;
    snn_out_kernel<<<(int)(nbt / 16), 256, 0, stream>>>(out1, w_out, b_out, out0);

    // 3) passthrough copy of x
    const int n4 = Bq * Tq * Sq / 4;
    copy_x_kernel<<<(n4 + 255) / 256, 256, 0, stream>>>((const float4*)x, (float4*)out2, n4);
}